// Round 6
// baseline (209.945 us; speedup 1.0000x reference)
//
#include <hip/hip_runtime.h>
#include <hip/hip_bf16.h>

// GAT layer, MI355X. B=32, N=512, Fin=256, F=64, H=8. fp32 in / fp32 out.
// R6: two kernels. k_h: h = x@W per (b,h) via MFMA -> hT bf16 in d_ws, plus
// s_src/s_dst computed in-register (shfl butterfly over C-layout) pre-scaled
// by log2(e). k_attn: per (b,h), hT staged to LDS with XOR-swizzled 16B
// blocks (uniform banks, no padding -> 64KB, 2 blocks/CU), barrier-free
// inner loop: P = adj * exp2(max(e,0.2e)) packed bf16, 4 PV MFMAs + 1
// ones-MFMA for row sums (lands in C-layout, no shuffles/LDS). R5 lesson:
// latency hiding needs per-thread ILP (it=4) as much as wave count.

#define ALPHA 0.2f

typedef __bf16 bf16x8 __attribute__((ext_vector_type(8)));
typedef __bf16 bf16x4 __attribute__((ext_vector_type(4)));
typedef float  f32x4  __attribute__((ext_vector_type(4)));

#if __has_builtin(__builtin_amdgcn_exp2f)
#define EXP2(x) __builtin_amdgcn_exp2f(x)
#define ESCALE  1.4426950408889634f   // scores pre-scaled by log2(e)
#else
#define EXP2(x) __expf(x)
#define ESCALE  1.0f
#endif

__device__ inline bf16x8 ld8(const float* p) {
    float4 a0 = *(const float4*)p;
    float4 a1 = *(const float4*)(p + 4);
    bf16x8 r;
    r[0]=(__bf16)a0.x; r[1]=(__bf16)a0.y; r[2]=(__bf16)a0.z; r[3]=(__bf16)a0.w;
    r[4]=(__bf16)a1.x; r[5]=(__bf16)a1.y; r[6]=(__bf16)a1.z; r[7]=(__bf16)a1.w;
    return r;
}

// ---------------- kernel 1: h = x@W -> hT[bh][f][j] bf16 + scores ----------
#define WT_STRIDE 264
__global__ __launch_bounds__(512) void k_h(const float* __restrict__ x,
                                           const float* __restrict__ W,
                                           const float* __restrict__ a,
                                           __bf16* __restrict__ hT,
                                           float* __restrict__ ssrc,
                                           float* __restrict__ sdst) {
    __shared__ __bf16 WT[64][WT_STRIDE];
    const int h = blockIdx.x, b = blockIdx.y;
    const int tid = threadIdx.x;
    const int wave = tid >> 6, lane = tid & 63;
    const int quad = lane >> 4, col = lane & 15;
    const long bh = b * 8 + h;

    {
        int c = tid & 63, k0 = tid >> 6;             // coalesced in c
        #pragma unroll 4
        for (int t = 0; t < 32; ++t)
            WT[c][k0 + t * 8] = (__bf16)W[(long)(k0 + t * 8) * 512 + h * 64 + c];
    }
    float asv[4], adv[4];
    #pragma unroll
    for (int nt = 0; nt < 4; ++nt) {
        asv[nt] = a[h * 128 + nt * 16 + col];
        adv[nt] = a[h * 128 + 64 + nt * 16 + col];
    }
    __syncthreads();

    const float* xb = x + (long)b * 512 * 256;
    f32x4 acc[4][4] = {};
    for (int ks = 0; ks < 8; ++ks) {                 // K = 256
        int k0 = ks * 32 + quad * 8;
        bf16x8 av[4], bv[4];
        #pragma unroll
        for (int it = 0; it < 4; ++it)               // A[m=col][k=quad*8+u]
            av[it] = ld8(xb + (long)(wave * 64 + it * 16 + col) * 256 + k0);
        #pragma unroll
        for (int nt = 0; nt < 4; ++nt)               // B[k][n=col]
            bv[nt] = *(const bf16x8*)(&WT[nt * 16 + col][k0]);
        #pragma unroll
        for (int it = 0; it < 4; ++it)
            #pragma unroll
            for (int nt = 0; nt < 4; ++nt)
                acc[it][nt] = __builtin_amdgcn_mfma_f32_16x16x32_bf16(av[it], bv[nt], acc[it][nt], 0, 0, 0);
    }
    // write hT (C/D: row(node)=quad*4+r, col(f)=lane&15)
    #pragma unroll
    for (int it = 0; it < 4; ++it)
        #pragma unroll
        for (int nt = 0; nt < 4; ++nt) {
            int f = nt * 16 + col;
            int j = wave * 64 + it * 16 + quad * 4;
            bf16x4 pk = { (__bf16)acc[it][nt][0], (__bf16)acc[it][nt][1],
                          (__bf16)acc[it][nt][2], (__bf16)acc[it][nt][3] };
            *(bf16x4*)(hT + (bh * 64 + f) * 512 + j) = pk;
        }
    // scores: s[j] = sum_f h[j][f]*a[f]; 16 col-lanes hold f-slices of row j
    #pragma unroll
    for (int it = 0; it < 4; ++it)
        #pragma unroll
        for (int r = 0; r < 4; ++r) {
            float ps = 0.f, pd = 0.f;
            #pragma unroll
            for (int nt = 0; nt < 4; ++nt) {
                ps += acc[it][nt][r] * asv[nt];
                pd += acc[it][nt][r] * adv[nt];
            }
            #pragma unroll
            for (int off = 1; off < 16; off <<= 1) {  // butterfly over col
                ps += __shfl_xor(ps, off);
                pd += __shfl_xor(pd, off);
            }
            if (col == 0) {
                int j = wave * 64 + it * 16 + quad * 4 + r;
                ssrc[bh * 512 + j] = ps * ESCALE;
                sdst[bh * 512 + j] = pd * ESCALE;
            }
        }
}

// ---------------- kernel 2: attention, barrier-free inner loop -------------
__global__ __launch_bounds__(512, 4) void k_attn(const float* __restrict__ adj,
                                                 const __bf16* __restrict__ hT,
                                                 const float* __restrict__ ssrc,
                                                 const float* __restrict__ sdst,
                                                 float* __restrict__ out) {
    __shared__ __bf16 hTs[64 * 512];     // [f][j], 16B blocks XOR-swizzled
    __shared__ float  sdsts[512], ssrcs[512];
    const int h = blockIdx.x, b = blockIdx.y;
    const int tid = threadIdx.x;
    const int wave = tid >> 6, lane = tid & 63;
    const int quad = lane >> 4, col = lane & 15;
    const long bh = b * 8 + h;

    {   // stage hT: linear global reads, swizzled LDS writes (block ^= f&7)
        int f = tid >> 3, c8 = tid & 7, s = f & 7;
        const __bf16* src = hT + (bh * 64 + f) * 512;
        #pragma unroll
        for (int k = 0; k < 8; ++k) {
            int blk = k * 8 + c8;
            *(float4*)(&hTs[f * 512 + ((blk ^ s) * 8)]) = *(const float4*)(src + blk * 8);
        }
    }
    ssrcs[tid] = ssrc[bh * 512 + tid];
    sdsts[tid] = sdst[bh * 512 + tid];
    __syncthreads();

    float si[4];
    const float* arow[4];
    #pragma unroll
    for (int it = 0; it < 4; ++it) {
        int i = wave * 64 + it * 16 + col;           // A-row m = lane&15
        si[it]   = ssrcs[i];
        arow[it] = adj + ((long)b * 512 + i) * 512;
    }
    bf16x8 ones;
    #pragma unroll
    for (int u = 0; u < 8; ++u) ones[u] = (__bf16)1.0f;

    f32x4 acc[4][4] = {};
    f32x4 accs[4]   = {};                            // row sums via P@ones
    for (int ks = 0; ks < 16; ++ks) {                // K = 512 neighbors
        int j0 = ks * 32 + quad * 8;
        f32x4 s0 = *(const f32x4*)&sdsts[j0];
        f32x4 s1 = *(const f32x4*)&sdsts[j0 + 4];
        float sd[8] = {s0[0],s0[1],s0[2],s0[3],s1[0],s1[1],s1[2],s1[3]};
        bf16x8 bv[4];
        int sblk = ((ks * 4 + quad) ^ (col & 7)) * 8;  // swizzle read-back
        #pragma unroll
        for (int nt = 0; nt < 4; ++nt)
            bv[nt] = *(const bf16x8*)(&hTs[(nt * 16 + col) * 512 + sblk]);
        bf16x8 P[4];
        #pragma unroll
        for (int it = 0; it < 4; ++it) {
            float4 a0 = *(const float4*)(arow[it] + j0);
            float4 a1 = *(const float4*)(arow[it] + j0 + 4);
            float am[8] = {a0.x,a0.y,a0.z,a0.w,a1.x,a1.y,a1.z,a1.w};
            #pragma unroll
            for (int u = 0; u < 8; ++u) {
                float e = si[it] + sd[u];
                float l = fmaxf(e, ALPHA * e);       // lrelu (scale-invariant)
                float p = am[u] * EXP2(l);           // adj in {0,1}: mask=mul
                P[it][u] = (__bf16)p;
            }
        }
        #pragma unroll
        for (int it = 0; it < 4; ++it) {
            #pragma unroll
            for (int nt = 0; nt < 4; ++nt)
                acc[it][nt] = __builtin_amdgcn_mfma_f32_16x16x32_bf16(P[it], bv[nt], acc[it][nt], 0, 0, 0);
            accs[it] = __builtin_amdgcn_mfma_f32_16x16x32_bf16(P[it], ones, accs[it], 0, 0, 0);
        }
    }
    // epilogue: accs C-layout row = quad*4+r matches acc rows; no barrier
    #pragma unroll
    for (int it = 0; it < 4; ++it)
        #pragma unroll
        for (int r = 0; r < 4; ++r) {
            float s = accs[it][r];
            float inv = (s > 0.f) ? 1.0f / s : 0.f;
            int i = wave * 64 + it * 16 + quad * 4 + r;
            float* orow = out + ((long)b * 512 + i) * 512 + h * 64;
            #pragma unroll
            for (int nt = 0; nt < 4; ++nt)
                orow[nt * 16 + col] = acc[it][nt][r] * inv;
        }
}

// ---------------- fallback: R4's proven fused kernel (ws too small) --------
#define HT_STRIDE 520
struct SmemF {
    __bf16 hT[64][HT_STRIDE];
    __bf16 WT[64][WT_STRIDE];
    float  ssrc[512], sdst[512], rsum[512];
    float  asrc[64], adst[64];
};
__global__ __launch_bounds__(512, 1) void k_gat_fused(const float* __restrict__ x,
                                                      const float* __restrict__ adj,
                                                      const float* __restrict__ W,
                                                      const float* __restrict__ a,
                                                      float* __restrict__ out) {
    __shared__ SmemF sm;
    const int h = blockIdx.x, b = blockIdx.y;
    const int tid = threadIdx.x;
    const int wave = tid >> 6, lane = tid & 63;
    const int quad = lane >> 4, col = lane & 15;
    if (tid < 128) {
        float v = a[h * 128 + tid];
        if (tid < 64) sm.asrc[tid] = v; else sm.adst[tid - 64] = v;
    }
    {
        int c = tid & 63, k0 = tid >> 6;
        #pragma unroll 4
        for (int t = 0; t < 32; ++t)
            sm.WT[c][k0 + t * 8] = (__bf16)W[(long)(k0 + t * 8) * 512 + h * 64 + c];
    }
    __syncthreads();
    {
        const float* xb = x + (long)b * 512 * 256;
        f32x4 acc[4][4] = {};
        for (int ks = 0; ks < 8; ++ks) {
            int k0 = ks * 32 + quad * 8;
            bf16x8 av[4], bv[4];
            #pragma unroll
            for (int it = 0; it < 4; ++it)
                av[it] = ld8(xb + (long)(wave * 64 + it * 16 + col) * 256 + k0);
            #pragma unroll
            for (int nt = 0; nt < 4; ++nt)
                bv[nt] = *(const bf16x8*)(&sm.WT[nt * 16 + col][k0]);
            #pragma unroll
            for (int it = 0; it < 4; ++it)
                #pragma unroll
                for (int nt = 0; nt < 4; ++nt)
                    acc[it][nt] = __builtin_amdgcn_mfma_f32_16x16x32_bf16(av[it], bv[nt], acc[it][nt], 0, 0, 0);
        }
        #pragma unroll
        for (int it = 0; it < 4; ++it)
            #pragma unroll
            for (int nt = 0; nt < 4; ++nt) {
                int f = nt * 16 + col;
                int j = wave * 64 + it * 16 + quad * 4;
                bf16x4 pk = { (__bf16)acc[it][nt][0], (__bf16)acc[it][nt][1],
                              (__bf16)acc[it][nt][2], (__bf16)acc[it][nt][3] };
                *(bf16x4*)(&sm.hT[f][j]) = pk;
            }
    }
    __syncthreads();
    {
        float as = 0.f, ad = 0.f;
        #pragma unroll 8
        for (int f = 0; f < 64; ++f) {
            float v = (float)sm.hT[f][tid];
            as += v * sm.asrc[f];
            ad += v * sm.adst[f];
        }
        sm.ssrc[tid] = as;
        sm.sdst[tid] = ad;
    }
    __syncthreads();
    {
        float si[4], sacc[4] = {0.f, 0.f, 0.f, 0.f};
        const float* arow[4];
        #pragma unroll
        for (int it = 0; it < 4; ++it) {
            int i = wave * 64 + it * 16 + col;
            si[it]   = sm.ssrc[i];
            arow[it] = adj + ((long)(b * 512 + i)) * 512;
        }
        f32x4 acc[4][4] = {};
        for (int ks = 0; ks < 16; ++ks) {
            int j0 = ks * 32 + quad * 8;
            f32x4 s0 = *(const f32x4*)&sm.sdst[j0];
            f32x4 s1 = *(const f32x4*)&sm.sdst[j0 + 4];
            float sd[8] = {s0[0],s0[1],s0[2],s0[3],s1[0],s1[1],s1[2],s1[3]};
            bf16x8 P[4];
            #pragma unroll
            for (int it = 0; it < 4; ++it) {
                float4 a0 = *(const float4*)(arow[it] + j0);
                float4 a1 = *(const float4*)(arow[it] + j0 + 4);
                float am[8] = {a0.x,a0.y,a0.z,a0.w,a1.x,a1.y,a1.z,a1.w};
                #pragma unroll
                for (int u = 0; u < 8; ++u) {
                    float e = si[it] + sd[u];
                    e = e > 0.f ? e : ALPHA * e;
                    float p = (am[u] > 0.f) ? __expf(e) : 0.f;
                    __bf16 pb = (__bf16)p;
                    sacc[it] += (float)pb;
                    P[it][u] = pb;
                }
            }
            #pragma unroll
            for (int nt = 0; nt < 4; ++nt) {
                bf16x8 bv = *(const bf16x8*)(&sm.hT[nt * 16 + col][j0]);
                #pragma unroll
                for (int it = 0; it < 4; ++it)
                    acc[it][nt] = __builtin_amdgcn_mfma_f32_16x16x32_bf16(P[it], bv, acc[it][nt], 0, 0, 0);
            }
        }
        #pragma unroll
        for (int it = 0; it < 4; ++it) {
            float s = sacc[it];
            s += __shfl_xor(s, 16);
            s += __shfl_xor(s, 32);
            if (quad == 0) sm.rsum[wave * 64 + it * 16 + col] = s;
        }
        __syncthreads();
        #pragma unroll
        for (int it = 0; it < 4; ++it)
            #pragma unroll
            for (int r = 0; r < 4; ++r) {
                int i = wave * 64 + it * 16 + quad * 4 + r;
                float s = sm.rsum[i];
                float inv = (s > 0.f) ? 1.0f / s : 0.f;
                float* orow = out + ((long)(b * 512 + i)) * 512 + h * 64;
                #pragma unroll
                for (int nt = 0; nt < 4; ++nt)
                    orow[nt * 16 + col] = acc[it][nt][r] * inv;
            }
    }
}

// ---------------- launch ---------------------------------------------------
extern "C" void kernel_launch(void* const* d_in, const int* in_sizes, int n_in,
                              void* d_out, int out_size, void* d_ws, size_t ws_size,
                              hipStream_t stream) {
    const float* x   = (const float*)d_in[0];   // (32,512,256)
    const float* adj = (const float*)d_in[1];   // (32,512,512), {0,1}
    const float* W   = (const float*)d_in[2];   // (256,512)
    const float* a   = (const float*)d_in[3];   // (8,128)
    float* out = (float*)d_out;                 // (32,512,512)

    const size_t WS_NEED = 16777216 + 2 * 524288;   // hT + ssrc + sdst
    if (ws_size >= WS_NEED) {
        __bf16* hT   = (__bf16*)d_ws;
        float*  ssrc = (float*)((char*)d_ws + 16777216);
        float*  sdst = (float*)((char*)d_ws + 16777216 + 524288);
        k_h   <<<dim3(8, 32), 512, 0, stream>>>(x, W, a, hT, ssrc, sdst);
        k_attn<<<dim3(8, 32), 512, 0, stream>>>(adj, hT, ssrc, sdst, out);
    } else {
        k_gat_fused<<<dim3(8, 32), 512, 0, stream>>>(x, adj, W, a, out);
    }
}

// Round 7
// 140.861 us; speedup vs baseline: 1.4904x; 1.4904x over previous
//
#include <hip/hip_runtime.h>
#include <hip/hip_bf16.h>

// GAT layer, MI355X. B=32, N=512, Fin=256, F=64, H=8. fp32 in / fp32 out.
// R7 = R4's proven fused kernel (best: 73.7us) + three targeted changes:
//  1. b-major grid (32,8): linear id = b + 32h -> XCD = id%8 = b%8, so all
//     8 h-blocks of a batch share one XCD's L2 -> adj[b]/x[b] fetched ~once
//     (R6 showed 8x adj re-fetch: 145MB for k_attn alone).
//  2. software-pipelined adj prefetch in stage 3 (R4's ~80% stall = loads
//     serialized behind P-gen; now ks+1 loads fly over ks compute).
//  3. VALU diet: row sums via P@ones MFMA (drops sacc adds + shuffles +
//     rsum LDS + barrier; validated in R6), exp2 with log2e pre-folded
//     into `a`, mask by multiply (adj in {0,1}).

#define ALPHA  0.2f
#define ESCALE 1.4426950408889634f   // log2(e), folded into a at stage 0

typedef __bf16 bf16x8 __attribute__((ext_vector_type(8)));
typedef __bf16 bf16x4 __attribute__((ext_vector_type(4)));
typedef float  f32x4  __attribute__((ext_vector_type(4)));

#if __has_builtin(__builtin_amdgcn_exp2f)
#define EXP2(x) __builtin_amdgcn_exp2f(x)
#else
#define EXP2(x) exp2f(x)
#endif

#define HT_STRIDE 520   // 512+8: +4-bank shift per f-row
#define WT_STRIDE 264   // 256+8

struct Smem {
    __bf16 hT[64][HT_STRIDE];       // h^T tile [f][j]   66,560 B
    __bf16 WT[64][WT_STRIDE];       // W cols [n][k]     33,792 B
    float  ssrc[512], sdst[512];    //                    4,096 B
    float  asrc[64], adst[64];      //                      512 B
};                                  // 104,960 B -> 1 block/CU

__device__ inline bf16x8 ld8(const float* p) {
    float4 a0 = *(const float4*)p;
    float4 a1 = *(const float4*)(p + 4);
    bf16x8 r;
    r[0]=(__bf16)a0.x; r[1]=(__bf16)a0.y; r[2]=(__bf16)a0.z; r[3]=(__bf16)a0.w;
    r[4]=(__bf16)a1.x; r[5]=(__bf16)a1.y; r[6]=(__bf16)a1.z; r[7]=(__bf16)a1.w;
    return r;
}

__global__ __launch_bounds__(512, 1) void k_gat(const float* __restrict__ x,
                                                const float* __restrict__ adj,
                                                const float* __restrict__ W,
                                                const float* __restrict__ a,
                                                float* __restrict__ out) {
    __shared__ Smem sm;
    const int b = blockIdx.x, h = blockIdx.y;    // b-major: h-blocks share XCD
    const int tid  = threadIdx.x;
    const int wave = tid >> 6, lane = tid & 63;
    const int quad = lane >> 4, col = lane & 15;

    // stage 0: a * log2e -> LDS; W head-slice fp32->bf16 -> LDS
    if (tid < 128) {
        float v = a[h * 128 + tid] * ESCALE;
        if (tid < 64) sm.asrc[tid] = v; else sm.adst[tid - 64] = v;
    }
    {
        int c = tid & 63, k0 = tid >> 6;             // coalesced in c
        #pragma unroll 4
        for (int t = 0; t < 32; ++t)
            sm.WT[c][k0 + t * 8] = (__bf16)W[(long)(k0 + t * 8) * 512 + h * 64 + c];
    }
    __syncthreads();

    // stage 1: h = x[b] @ W[:,h-block] -> hT[f][j]  (MFMA 16x16x32)
    {
        const float* xb = x + (long)b * 512 * 256;
        f32x4 acc[4][4] = {};
        for (int ks = 0; ks < 8; ++ks) {             // K = 256
            int k0 = ks * 32 + quad * 8;
            bf16x8 av[4], bv[4];
            #pragma unroll
            for (int it = 0; it < 4; ++it)           // A[m=col][k=quad*8+u]
                av[it] = ld8(xb + (long)(wave * 64 + it * 16 + col) * 256 + k0);
            #pragma unroll
            for (int nt = 0; nt < 4; ++nt)           // B[k][n=col]
                bv[nt] = *(const bf16x8*)(&sm.WT[nt * 16 + col][k0]);
            #pragma unroll
            for (int it = 0; it < 4; ++it)
                #pragma unroll
                for (int nt = 0; nt < 4; ++nt)
                    acc[it][nt] = __builtin_amdgcn_mfma_f32_16x16x32_bf16(av[it], bv[nt], acc[it][nt], 0, 0, 0);
        }
        #pragma unroll
        for (int it = 0; it < 4; ++it)
            #pragma unroll
            for (int nt = 0; nt < 4; ++nt) {
                int f = nt * 16 + col;               // C/D: col=f, row=node
                int j = wave * 64 + it * 16 + quad * 4;
                bf16x4 pk = { (__bf16)acc[it][nt][0], (__bf16)acc[it][nt][1],
                              (__bf16)acc[it][nt][2], (__bf16)acc[it][nt][3] };
                *(bf16x4*)(&sm.hT[f][j]) = pk;
            }
    }
    __syncthreads();

    // stage 2: s_src[j], s_dst[j] = h_j . (a*log2e)
    {
        float as = 0.f, ad = 0.f;
        #pragma unroll 8
        for (int f = 0; f < 64; ++f) {
            float v = (float)sm.hT[f][tid];
            as += v * sm.asrc[f];
            ad += v * sm.adst[f];
        }
        sm.ssrc[tid] = as;
        sm.sdst[tid] = ad;
    }
    __syncthreads();

    // stage 3: P-gen + P@h MFMA, software-pipelined adj loads, no barriers
    {
        float si[4];
        const float* arow[4];
        #pragma unroll
        for (int it = 0; it < 4; ++it) {
            int i = wave * 64 + it * 16 + col;       // A-row m = lane&15
            si[it]   = sm.ssrc[i];
            arow[it] = adj + ((long)b * 512 + i) * 512;
        }
        bf16x8 ones;
        #pragma unroll
        for (int u = 0; u < 8; ++u) ones[u] = (__bf16)1.0f;

        f32x4 acc[4][4] = {};
        f32x4 accs[4]   = {};                        // row sums via P@ones
        float4 pa0[4], pa1[4];                       // prefetch registers
        #pragma unroll
        for (int it = 0; it < 4; ++it) {             // prefetch ks=0
            pa0[it] = *(const float4*)(arow[it] + quad * 8);
            pa1[it] = *(const float4*)(arow[it] + quad * 8 + 4);
        }
        for (int ks = 0; ks < 16; ++ks) {            // K = 512 neighbors
            int j0 = ks * 32 + quad * 8;
            f32x4 s0 = *(const f32x4*)&sm.sdst[j0];
            f32x4 s1 = *(const f32x4*)&sm.sdst[j0 + 4];
            float sd[8] = {s0[0],s0[1],s0[2],s0[3],s1[0],s1[1],s1[2],s1[3]};
            float am[4][8];
            #pragma unroll
            for (int it = 0; it < 4; ++it) {         // consume prefetch
                am[it][0]=pa0[it].x; am[it][1]=pa0[it].y;
                am[it][2]=pa0[it].z; am[it][3]=pa0[it].w;
                am[it][4]=pa1[it].x; am[it][5]=pa1[it].y;
                am[it][6]=pa1[it].z; am[it][7]=pa1[it].w;
            }
            if (ks < 15) {                           // issue ks+1 loads now;
                #pragma unroll                       // they fly over P-gen+MFMA
                for (int it = 0; it < 4; ++it) {
                    pa0[it] = *(const float4*)(arow[it] + j0 + 32);
                    pa1[it] = *(const float4*)(arow[it] + j0 + 36);
                }
            }
            bf16x8 P[4];
            #pragma unroll
            for (int it = 0; it < 4; ++it)
                #pragma unroll
                for (int u = 0; u < 8; ++u) {
                    float e = si[it] + sd[u];        // pre-scaled by log2e
                    float l = fmaxf(e, ALPHA * e);   // lrelu (pos-scale-invariant)
                    float p = am[it][u] * EXP2(l);   // mask by multiply
                    P[it][u] = (__bf16)p;
                }
            bf16x8 bv[4];
            #pragma unroll
            for (int nt = 0; nt < 4; ++nt)
                bv[nt] = *(const bf16x8*)(&sm.hT[nt * 16 + col][j0]);
            #pragma unroll
            for (int it = 0; it < 4; ++it) {
                #pragma unroll
                for (int nt = 0; nt < 4; ++nt)
                    acc[it][nt] = __builtin_amdgcn_mfma_f32_16x16x32_bf16(P[it], bv[nt], acc[it][nt], 0, 0, 0);
                accs[it] = __builtin_amdgcn_mfma_f32_16x16x32_bf16(P[it], ones, accs[it], 0, 0, 0);
            }
        }
        // epilogue: accs rows (quad*4+r) align with acc rows; no barrier
        #pragma unroll
        for (int it = 0; it < 4; ++it)
            #pragma unroll
            for (int r = 0; r < 4; ++r) {
                float s = accs[it][r];
                float inv = (s > 0.f) ? 1.0f / s : 0.f;
                int i = wave * 64 + it * 16 + quad * 4 + r;
                float* orow = out + ((long)b * 512 + i) * 512 + h * 64;
                #pragma unroll
                for (int nt = 0; nt < 4; ++nt)
                    orow[nt * 16 + col] = acc[it][nt][r] * inv;
            }
    }
}

// ---------------- launch ---------------------------------------------------
extern "C" void kernel_launch(void* const* d_in, const int* in_sizes, int n_in,
                              void* d_out, int out_size, void* d_ws, size_t ws_size,
                              hipStream_t stream) {
    const float* x   = (const float*)d_in[0];   // (32,512,256)
    const float* adj = (const float*)d_in[1];   // (32,512,512), {0,1}
    const float* W   = (const float*)d_in[2];   // (256,512)
    const float* a   = (const float*)d_in[3];   // (8,128)
    float* out = (float*)d_out;                 // (32,512,512)
    (void)d_ws; (void)ws_size;

    k_gat<<<dim3(32, 8), 512, 0, stream>>>(x, adj, W, a, out);
}